// Round 1
// 125.638 us; speedup vs baseline: 1.0200x; 1.0200x over previous
//
#include <hip/hip_runtime.h>
#include <math.h>

// Problem constants (fixed by the reference):
#define NROWS 65536   // B*H*Wd = 8*64*128
#define DD    272     // capsule feature dim
#define NC    19      // num classes
#define NP    524288  // total points
#define NSEG  4096    // total instances
#define PS    20      // padded proj row stride (16B-aligned float4 rows)

#define PROJ_BLOCKS   (NROWS / 64)     // 1024
#define BOUND_BLOCKS  (NP / 256)       // 2048

// ---------------------------------------------------------------------------
// Fused kernel A:
//   blocks [0, 1024): proj[row][c] = sum_d X[row][d] * W[d][c]  (stride-20 pad)
//     64 rows/block, 256 threads; wave q handles d % 4 == q.
//     v2: double-buffered LDS staging -> ONE barrier per 16-float chunk
//     (was 2), and a 2-chunk-deep global prefetch so each load batch has
//     ~2 compute phases of latency cover instead of <1.
//   blocks [1024, 3072): segment boundary extraction from sorted seg[]:
//     bnd[s] = lower_bound(seg, s); bnd[NSEG] = NP.
// ---------------------------------------------------------------------------
__global__ __launch_bounds__(256) void proj_bounds_kernel(
    const float* __restrict__ X, const float* __restrict__ W,
    const int* __restrict__ seg, float* __restrict__ proj,
    int* __restrict__ bnd) {
  const int t = threadIdx.x;

  if (blockIdx.x >= PROJ_BLOCKS) {
    // ---- boundary extraction ----
    const int p = (blockIdx.x - PROJ_BLOCKS) * 256 + t;
    const int cur  = seg[p];
    const int prev = (p == 0) ? -1 : seg[p - 1];
    for (int s = prev + 1; s <= cur; ++s) bnd[s] = p;   // total writes <= NSEG+1
    if (p == NP - 1) {
      for (int s = cur + 1; s <= NSEG; ++s) bnd[s] = NP;
    }
    return;
  }

  // ---- projection GEMM ----
  const int lane = t & 63;
  const int q    = __builtin_amdgcn_readfirstlane(t >> 6);  // wave-uniform residue
  const int row0 = blockIdx.x * 64;

  __shared__ float Xs[2][64 * 17];     // double-buffered: 64 rows x 16, pad 17
  __shared__ float R[4 * 64 * NC];     // per-wave partials for reduction

  float acc[NC];
#pragma unroll
  for (int c = 0; c < NC; ++c) acc[c] = 0.f;

  const int r_ld = t >> 2;             // staging row
  const int c4   = t & 3;              // float4 slot within 16-float chunk
  const float* gsrc = X + (size_t)(row0 + r_ld) * DD + c4 * 4;
  float* dst0 = &Xs[0][r_ld * 17 + c4 * 4];
  float* dst1 = &Xs[1][r_ld * 17 + c4 * 4];

  // 19 fmas per k-step, 4 k-steps per 16-float chunk, per wave-uniform residue q
#define COMPUTE(CH, BUF) do {                                        \
    const int d0_ = (CH) * 16;                                       \
    const float* xrow_ = &Xs[BUF][lane * 17];                        \
    _Pragma("unroll")                                                \
    for (int k = 0; k < 4; ++k) {                                    \
      const int c16_ = q + 4 * k;                                    \
      const float x_ = xrow_[c16_];          /* stride 17: 2-way, free */ \
      const float* wr_ = W + (d0_ + c16_) * NC;  /* uniform -> s_load */  \
      _Pragma("unroll")                                              \
      for (int c = 0; c < NC; ++c) acc[c] = fmaf(x_, wr_[c], acc[c]); \
    }                                                                \
  } while (0)

  // Prologue: chunk0 -> buf0; chunk1,2 in flight.
  float4 va = *(const float4*)(gsrc);            // chunk 0
  float4 vb = *(const float4*)(gsrc + 16);       // chunk 1
  dst0[0] = va.x; dst0[1] = va.y; dst0[2] = va.z; dst0[3] = va.w;
  va = *(const float4*)(gsrc + 32);              // chunk 2
  __syncthreads();                               // buf0 (chunk 0) ready

  // Steady state: 8 pair-iterations cover chunks 0..15; chunk 16 in epilogue.
  // Invariants at top of iter i (c0 = 2i):
  //   buf0 holds chunk c0; vb holds chunk c0+1; va holds chunk c0+2.
  for (int i = 0; i < 8; ++i) {
    const int c0 = 2 * i;
    // stage chunk c0+1 into buf1 (readers of buf1 finished before last barrier)
    dst1[0] = vb.x; dst1[1] = vb.y; dst1[2] = vb.z; dst1[3] = vb.w;
    if (c0 + 3 <= 16)
      vb = *(const float4*)(gsrc + (c0 + 3) * 16);   // 2 phases of cover
    COMPUTE(c0, 0);
    __syncthreads();
    // stage chunk c0+2 into buf0 (its readers just passed the barrier)
    dst0[0] = va.x; dst0[1] = va.y; dst0[2] = va.z; dst0[3] = va.w;
    if (c0 + 4 <= 16)
      va = *(const float4*)(gsrc + (c0 + 4) * 16);
    COMPUTE(c0 + 1, 1);
    __syncthreads();
  }
  COMPUTE(16, 0);                                // chunk 16 staged in iter 7
#undef COMPUTE

  // cross-wave reduction of the 4 d-residue partials
#pragma unroll
  for (int c = 0; c < NC; ++c) R[(q * 64 + lane) * NC + c] = acc[c];
  __syncthreads();
#pragma unroll
  for (int j = 0; j < 5; ++j) {
    int f = t + 256 * j;               // 0..1279 covers 64 rows x 20 cols
    int r = f / PS;
    int c = f % PS;
    float s = 0.f;
    if (c < NC) {
      s = R[r * NC + c] + R[(64 + r) * NC + c] +
          R[(128 + r) * NC + c] + R[(192 + r) * NC + c];
    }
    proj[(size_t)row0 * PS + f] = s;   // contiguous coalesced store (pad = 0)
  }
}

// ---------------------------------------------------------------------------
// Kernel B: per-segment mean of gathered proj rows + bias + sigmoid.
// v2: 4 segments per 256-thread block (one per wave) -> up to 32 waves/CU
// (was capped at 16 by the workgroup/CU limit with 64-thread blocks), and a
// software-pipelined point_idx prefetch to break the idx->gather chain.
// ---------------------------------------------------------------------------
__global__ __launch_bounds__(256, 8) void pool_kernel(
    const float* __restrict__ proj, const int* __restrict__ point_idx,
    const int* __restrict__ bnd, const float* __restrict__ bias,
    float* __restrict__ out) {
  const int wave = threadIdx.x >> 6;
  const int lane = threadIdx.x & 63;
  const int s    = blockIdx.x * 4 + wave;
  const int start = bnd[s];
  const int end   = bnd[s + 1];

  float a[PS];
#pragma unroll
  for (int j = 0; j < PS; ++j) a[j] = 0.f;

  int p  = start + lane;
  int pi = (p < end) ? point_idx[p] : 0;
  while (p < end) {
    const int pn      = p + 64;
    const int pi_next = (pn < end) ? point_idx[pn] : 0;  // prefetch next idx
    const float4* row = (const float4*)(proj + (size_t)pi * PS);  // 80B aligned
    float4 r0 = row[0], r1 = row[1], r2 = row[2], r3 = row[3], r4 = row[4];
    a[0]  += r0.x; a[1]  += r0.y; a[2]  += r0.z; a[3]  += r0.w;
    a[4]  += r1.x; a[5]  += r1.y; a[6]  += r1.z; a[7]  += r1.w;
    a[8]  += r2.x; a[9]  += r2.y; a[10] += r2.z; a[11] += r2.w;
    a[12] += r3.x; a[13] += r3.y; a[14] += r3.z; a[15] += r3.w;
    a[16] += r4.x; a[17] += r4.y; a[18] += r4.z; a[19] += r4.w;
    pi = pi_next;
    p  = pn;
  }

  // butterfly reduce the 19 live accumulators across 64 lanes
#pragma unroll
  for (int off = 32; off > 0; off >>= 1) {
#pragma unroll
    for (int j = 0; j < NC; ++j) a[j] += __shfl_xor(a[j], off);
  }

  if (lane == 0) {
    const float inv = 1.f / fmaxf((float)(end - start), 1.f);
#pragma unroll
    for (int c = 0; c < NC; ++c) {
      float m = a[c] * inv + bias[c];
      out[s * NC + c] = 1.f / (1.f + expf(-m));
    }
  }
}

// ---------------------------------------------------------------------------
// Fallback (only if workspace is too small): direct full-D gather per segment.
// ---------------------------------------------------------------------------
__global__ __launch_bounds__(256) void fallback_kernel(
    const float* __restrict__ X, const float* __restrict__ W,
    const float* __restrict__ bias, const int* __restrict__ point_idx,
    const int* __restrict__ seg, float* __restrict__ out) {
  const int s = blockIdx.x;
  const int t = threadIdx.x;
  __shared__ float Ps[DD];

  int lo = 0, hi = NP;
  while (lo < hi) { int mid = (lo + hi) >> 1; if (seg[mid] <  s) lo = mid + 1; else hi = mid; }
  const int start = lo;
  hi = NP;
  while (lo < hi) { int mid = (lo + hi) >> 1; if (seg[mid] <= s) lo = mid + 1; else hi = mid; }
  const int end = lo;

  float a0 = 0.f, a1 = 0.f;
  for (int p = start; p < end; ++p) {
    const int pi = point_idx[p];
    const float* row = X + (size_t)pi * DD;
    a0 += row[t];
    if (t < DD - 256) a1 += row[256 + t];
  }
  const float inv = 1.f / fmaxf((float)(end - start), 1.f);
  Ps[t] = a0 * inv;
  if (t < DD - 256) Ps[256 + t] = a1 * inv;
  __syncthreads();

  if (t < NC) {
    float acc = bias[t];
    for (int d = 0; d < DD; ++d) acc = fmaf(Ps[d], W[d * NC + t], acc);
    out[s * NC + t] = 1.f / (1.f + expf(-acc));
  }
}

extern "C" void kernel_launch(void* const* d_in, const int* in_sizes, int n_in,
                              void* d_out, int out_size, void* d_ws, size_t ws_size,
                              hipStream_t stream) {
  const float* X         = (const float*)d_in[0];  // [65536, 272]
  const float* W         = (const float*)d_in[1];  // [272, 19]
  const float* bias      = (const float*)d_in[2];  // [19]
  const int*   point_idx = (const int*)d_in[3];    // [P]
  const int*   seg       = (const int*)d_in[4];    // [P] sorted
  float*       out       = (float*)d_out;          // [4096, 19]

  const size_t proj_bytes = (size_t)NROWS * PS * sizeof(float);     // 5.24 MB
  const size_t need = proj_bytes + (size_t)(NSEG + 1) * sizeof(int);
  if (ws_size >= need) {
    float* proj = (float*)d_ws;
    int*   bnd  = (int*)((char*)d_ws + proj_bytes);
    proj_bounds_kernel<<<PROJ_BLOCKS + BOUND_BLOCKS, 256, 0, stream>>>(
        X, W, seg, proj, bnd);
    pool_kernel<<<NSEG / 4, 256, 0, stream>>>(proj, point_idx, bnd, bias, out);
  } else {
    fallback_kernel<<<NSEG, 256, 0, stream>>>(X, W, bias, point_idx, seg, out);
  }
}